// Round 5
// baseline (242.168 us; speedup 1.0000x reference)
//
#include <hip/hip_runtime.h>
#include <math.h>

#define B_ 64
#define F_ 32
#define S_ 512
#define P_ 96
#define E_ 8
#define H_ 2048
#define M_ 2048   // B_*F_ rows, m = b*F_ + f

// ---- k_experts tiling (m97-style): 256 threads, 128m x 128h tiles, BK=64 ----
#define BM 128
#define BH 128
#define BK 64
#define ZSPLIT 4
#define HPZ (H_ / ZSPLIT)   // 512 h per z-block
#define NHT (HPZ / BH)      // 4 h-chunks per block
#define NKC (S_ / BK)       // 8 k-chunks
#define HPITCH 136          // 128 + 8 skew

typedef __bf16 bf16x8 __attribute__((ext_vector_type(8)));
typedef __bf16 bf16x4 __attribute__((ext_vector_type(4)));
typedef float f32x4 __attribute__((ext_vector_type(4)));

#define MFMA16(a, b, c) __builtin_amdgcn_mfma_f32_16x16x32_bf16((a), (b), (c), 0, 0, 0)

// async global->LDS, 16B per lane; LDS dest is wave-uniform base + lane*16
#define GLL16(gp, lp) __builtin_amdgcn_global_load_lds(                     \
    (const __attribute__((address_space(1))) void*)(gp),                    \
    (__attribute__((address_space(3))) void*)(lp), 16, 0, 0)

// sigmoid-approx gelu: x * sigmoid(1.702 x)  (absmax 0.0098 measured — 17x margin)
__device__ __forceinline__ float fast_gelu(float x) {
  float e = __builtin_amdgcn_exp2f(-2.45546696f * x);
  return x * __builtin_amdgcn_rcpf(1.0f + e);
}

// =================== k_prep (256 threads): transposes + convert + gates + out-zero ===========
// blocks [0,256):      W1 strip transpose: (e, 64-h strip) x all 512 s -> w1t [E][H][S] bf16
// blocks [256,768):    W2 [E][H][P] f32 -> w2t [E][P][H] bf16 (64h x 48p tiles)
// blocks [768,1280):   x convert (8 elems/thread)
// blocks [1280,1792):  gates (4 rows per block)
// blocks [1792,1984):  zero d_out accumulation region
#define PREP_GRID 1984

__global__ __launch_bounds__(256) void k_prep(const float* __restrict__ x,
                                              const float* __restrict__ te,
                                              const float* __restrict__ Wg,
                                              const float* __restrict__ bg,
                                              const float* __restrict__ W1,
                                              const float* __restrict__ W2,
                                              __bf16* __restrict__ xbf,
                                              __bf16* __restrict__ w1t,
                                              __bf16* __restrict__ w2t,
                                              float* __restrict__ gates,
                                              float* __restrict__ out) {
  __shared__ __align__(16) __bf16 btile[256 * 68];   // 34,816 B (W1 strip)
  const int blk = blockIdx.x;
  const int tid = threadIdx.x;

  if (blk < 256) {                        // ---- W1 strip transpose: 64 h x 512 s
    int e = blk >> 5, hstrip = blk & 31;
    const float* src = W1 + (size_t)e * S_ * H_ + hstrip * 64;
    __bf16* dstb = w1t + (size_t)e * H_ * S_ + (size_t)(hstrip * 64) * S_;
#pragma unroll
    for (int pass = 0; pass < 2; ++pass) {
      // phase A: read [256 s][64 h] f32 (256 B contiguous per row), cast, LDS [s][h]
      {
        int rb = tid >> 2;                // row group base
        int hseg = (tid & 3) * 16;
#pragma unroll
        for (int it = 0; it < 4; ++it) {
          int r = it * 64 + rb;
          const float* srow = src + (size_t)(pass * 256 + r) * H_ + hseg;
#pragma unroll
          for (int k = 0; k < 4; ++k) {
            f32x4 v = *(const f32x4*)(srow + k * 4);
            bf16x4 o = {(__bf16)v[0], (__bf16)v[1], (__bf16)v[2], (__bf16)v[3]};
            *(bf16x4*)&btile[r * 68 + hseg + k * 4] = o;
          }
        }
      }
      __syncthreads();
      // phase B: column gather (2-way same-word broadcast) -> 128 B contiguous stores
      {
        int h = tid >> 2;
        int sseg = (tid & 3) * 64;
        __bf16* drow = dstb + (size_t)h * S_ + pass * 256 + sseg;
#pragma unroll
        for (int g = 0; g < 8; ++g) {
          bf16x8 o;
#pragma unroll
          for (int j = 0; j < 8; ++j) o[j] = btile[(sseg + g * 8 + j) * 68 + h];
          *(bf16x8*)(drow + g * 8) = o;
        }
      }
      __syncthreads();
    }
    return;
  }
  if (blk < 768) {                        // ---- W2 transpose: tile 64h x 48p
    float* tile = (float*)&btile[0];      // 64*49 f32
    int t = blk - 256;
    int e = t >> 6, hi = (t >> 1) & 31, ph = t & 1;
    const float* src = W2 + (size_t)e * H_ * P_ + (size_t)(hi * 64) * P_ + ph * 48;
    {
      int h = tid & 63;
      int seg = tid >> 6;
#pragma unroll
      for (int k = 0; k < 3; ++k) {
        f32x4 v = *(const f32x4*)(src + (size_t)h * P_ + seg * 12 + k * 4);
#pragma unroll
        for (int u = 0; u < 4; ++u) tile[h * 49 + seg * 12 + k * 4 + u] = v[u];
      }
    }
    __syncthreads();
    if (tid < 192) {
      int p = tid >> 2;
      int hb = (tid & 3) * 16;
      __bf16* dst = w2t + (size_t)e * P_ * H_ + (size_t)(ph * 48 + p) * H_ + hi * 64 + hb;
      bf16x8 o0, o1;
#pragma unroll
      for (int k = 0; k < 8; ++k) o0[k] = (__bf16)tile[(hb + k) * 49 + p];
#pragma unroll
      for (int k = 0; k < 8; ++k) o1[k] = (__bf16)tile[(hb + 8 + k) * 49 + p];
      *(bf16x8*)dst = o0;
      *(bf16x8*)(dst + 8) = o1;
    }
    return;
  }
  if (blk < 1280) {                       // ---- x convert
    size_t i = (size_t)(blk - 768) * 2048 + (size_t)tid * 8;
#pragma unroll
    for (int k = 0; k < 2; ++k) {
      f32x4 v = *(const f32x4*)(x + i + k * 4);
      bf16x4 o = {(__bf16)v[0], (__bf16)v[1], (__bf16)v[2], (__bf16)v[3]};
      *(bf16x4*)(xbf + i + k * 4) = o;
    }
    return;
  }
  if (blk < 1792) {                       // ---- gates: one wave per row m
    int wave = tid >> 6, lane = tid & 63;
    int m = (blk - 1280) * 4 + wave;
    const float* trow = te + (size_t)m * S_;
    float acc[E_];
#pragma unroll
    for (int e = 0; e < E_; ++e) acc[e] = 0.f;
    for (int s = lane; s < S_; s += 64) {
      float t = trow[s];
      const f32x4* wgr = (const f32x4*)(Wg + s * E_);
      f32x4 a = wgr[0], b = wgr[1];
      acc[0] += t * a[0]; acc[1] += t * a[1]; acc[2] += t * a[2]; acc[3] += t * a[3];
      acc[4] += t * b[0]; acc[5] += t * b[1]; acc[6] += t * b[2]; acc[7] += t * b[3];
    }
#pragma unroll
    for (int e = 0; e < E_; ++e) {
#pragma unroll
      for (int off = 32; off > 0; off >>= 1) acc[e] += __shfl_xor(acc[e], off, 64);
    }
    if (lane == 0) {
      float lg[E_];
      float m1 = -3.4e38f, m2 = -3.4e38f;
#pragma unroll
      for (int e = 0; e < E_; ++e) {
        float v = acc[e] + bg[e];
        lg[e] = v;
        if (v > m1) { m2 = m1; m1 = v; }
        else if (v > m2) { m2 = v; }
      }
      float den = 0.f, sm[E_];
#pragma unroll
      for (int e = 0; e < E_; ++e) { sm[e] = expf(lg[e] - m1); den += sm[e]; }
      float inv = 1.f / den;
      float dmax = -3.4e38f, dec[E_];
#pragma unroll
      for (int e = 0; e < E_; ++e) {
        float p = sm[e] * inv;
        float d = (lg[e] < m2) ? (10.f * logf(p + 1.f)) : (10.f * (expf(p) - 1.f));
        dec[e] = d;
        dmax = fmaxf(dmax, d);
      }
      float dden = 0.f;
#pragma unroll
      for (int e = 0; e < E_; ++e) { dec[e] = expf(dec[e] - dmax); dden += dec[e]; }
      float dinv = 1.f / dden;
#pragma unroll
      for (int e = 0; e < E_; ++e) gates[m * E_ + e] = dec[e] * dinv;
    }
    return;
  }
  // ---- zero d_out [0, M*P): 192 blocks x 1024 f32
  {
    size_t i = (size_t)(blk - 1792) * 1024 + (size_t)tid * 4;
    f32x4 z = {0.f, 0.f, 0.f, 0.f};
    *(f32x4*)(out + i) = z;
  }
}

// =================== k_experts: grid (E_, 16, ZSPLIT+1), 256 threads ===================
// Per block: 128m rows, 512h slice (4 chunks of 128). Per h-chunk:
//   GEMM1 (m97 structure): global_load_lds stages W1t[128h][64k] + X[128m][64k]
//   (X staged into the low 16 KB of Hs — lifetimes disjoint) with XOR granule
//   swizzle on the GLOBAL source address; ds_read_b128 frags -> MFMA.
//   gelu -> Hs[m][h]; GEMM2 accumulates acc2 (128m x 96p) across all 4 chunks.
// LDS = 16K (W1s) + 34.8K (Hs) = 51.2 KB -> 3 blocks/CU (12 waves/CU).
__global__ __launch_bounds__(256, 3) void k_experts(
    const __bf16* __restrict__ xbf,   // [M][S]
    const __bf16* __restrict__ w1t,   // [E][H][S]
    const __bf16* __restrict__ w2t,   // [E][P][H]
    const float* __restrict__ b1,     // [E][H]
    const float* __restrict__ b2,     // [E][P]
    const float* __restrict__ gates,  // [M][E]
    float* __restrict__ out)          // [M][P] (+2 loss slots)
{
  __shared__ __align__(16) __bf16 W1s[BH * BK];      // 16 KB [h][k] unpadded, swizzled
  __shared__ __align__(16) __bf16 Hs[BM * HPITCH];   // 34.8 KB; low 16 KB doubles as Xs

  __bf16* Xs = &Hs[0];   // alias: Xs lifetime = k-loop; Hs lifetime = gelu..GEMM2

  const int tid = threadIdx.x;

  if (blockIdx.z == ZSPLIT) {      // ---- loss block (others exit)
    if (blockIdx.x != 0 || blockIdx.y != 0) return;
    float* gsum = (float*)&Hs[0];
    float* cvs  = gsum + F_ * E_;
    float* ents = cvs + F_;
    int f = tid >> 3, e = tid & 7;
    float s = 0.f;
    for (int b = 0; b < B_; ++b) s += gates[(size_t)(b * F_ + f) * E_ + e];
    gsum[f * E_ + e] = s;
    __syncthreads();
    if (tid < F_) {
      float mean = 0.f;
#pragma unroll
      for (int k = 0; k < E_; ++k) mean += gsum[tid * E_ + k];
      mean *= (1.f / E_);
      float ss = 0.f;
#pragma unroll
      for (int k = 0; k < E_; ++k) { float d = gsum[tid * E_ + k] - mean; ss += d * d; }
      float var = (float)P_ * ss / (float)(E_ * P_ - 1);
      cvs[tid] = var / (mean * mean + 1e-10f);
      float ent = 0.f;
#pragma unroll
      for (int k = 0; k < E_; ++k) { float g = gsum[tid * E_ + k] * (1.f / B_); ent += -g * logf(g + 1e-8f); }
      ents[tid] = ent * (1.f / E_);
    }
    __syncthreads();
    if (tid == 0) {
      float a = 0.f, b = 0.f;
      for (int k = 0; k < F_; ++k) { a += cvs[k]; b += ents[k]; }
      out[(size_t)M_ * P_ + 0] = a;
      out[(size_t)M_ * P_ + 1] = b;
    }
    return;
  }

  const int wave = tid >> 6, lane = tid & 63;
  const int l15 = lane & 15, quad = lane >> 4;
  const int e = blockIdx.x;
  const int m0 = blockIdx.y * BM;
  const int hz = blockIdx.z * HPZ;

  // staging decomposition: lane -> (row-in-8-group, granule); swizzle sg^srl
  const int sg = lane & 7;
  const int srl = lane >> 3;
  const int gcol = ((sg ^ srl) * 8);    // swizzled source column (elements)

  const __bf16* xg = xbf + (size_t)(m0 + wave * 8 + srl) * S_ + gcol;
  const __bf16* w1base = w1t + ((size_t)e * H_ + hz + wave * 8 + srl) * S_ + gcol;
  const __bf16* w2z = w2t + (size_t)e * P_ * H_ + hz;

  const int hq = (wave >> 1) * 64;   // GEMM1 wave quadrant
  const int mq = (wave & 1) * 64;
  const int w32 = wave * 32;         // GEMM2 wave rows

  const f32x4 fz = {0.f, 0.f, 0.f, 0.f};
  f32x4 acc2[2][6];
#pragma unroll
  for (int rt = 0; rt < 2; ++rt)
#pragma unroll
    for (int j = 0; j < 6; ++j) acc2[rt][j] = fz;

  for (int ht = 0; ht < NHT; ++ht) {
    const __bf16* w1g = w1base + (size_t)(ht * BH) * S_;
    f32x4 acc1[4][4];
#pragma unroll
    for (int i = 0; i < 4; ++i)
#pragma unroll
      for (int j = 0; j < 4; ++j) acc1[i][j] = fz;

    for (int kc = 0; kc < NKC; ++kc) {
#pragma unroll
      for (int p = 0; p < 4; ++p) {
        GLL16(w1g + (size_t)(p * 32) * S_ + kc * BK, &W1s[(p * 32 + wave * 8) * BK]);
        GLL16(xg  + (size_t)(p * 32) * S_ + kc * BK, &Xs[(p * 32 + wave * 8) * BK]);
      }
      __syncthreads();   // vmcnt drain + barrier: staged tiles visible
#pragma unroll
      for (int kk = 0; kk < 2; ++kk) {
        bf16x8 a[4], b[4];
#pragma unroll
        for (int i = 0; i < 4; ++i) {
          int r = hq + i * 16 + l15;
          int g = kk * 4 + quad;
          a[i] = *(const bf16x8*)&W1s[r * BK + ((g ^ (r & 7)) * 8)];
        }
#pragma unroll
        for (int j = 0; j < 4; ++j) {
          int r = mq + j * 16 + l15;
          int g = kk * 4 + quad;
          b[j] = *(const bf16x8*)&Xs[r * BK + ((g ^ (r & 7)) * 8)];
        }
#pragma unroll
        for (int i = 0; i < 4; ++i)
#pragma unroll
          for (int j = 0; j < 4; ++j)
            acc1[i][j] = MFMA16(a[i], b[j], acc1[i][j]);
      }
      __syncthreads();   // reads done before next stage overwrites
    }

    // bias + gelu -> Hs[m][h] (C-layout: col=l15=m, row=quad*4+r=h-local)
    {
      const float* b1w = b1 + (size_t)e * H_ + hz + ht * BH + hq;
#pragma unroll
      for (int i = 0; i < 4; ++i) {
        f32x4 bv = *(const f32x4*)(b1w + i * 16 + quad * 4);
#pragma unroll
        for (int j = 0; j < 4; ++j) {
          bf16x4 hv;
#pragma unroll
          for (int r = 0; r < 4; ++r)
            hv[r] = (__bf16)fast_gelu(acc1[i][j][r] + bv[r]);
          *(bf16x4*)&Hs[(mq + j * 16 + l15) * HPITCH + hq + i * 16 + quad * 4] = hv;
        }
      }
    }
    __syncthreads();

    // GEMM2: acc2 += Hs[128m x 128h] @ W2chunk[128h x 96p]; B-frags direct from L1/L2-hot w2t
    {
      const __bf16* w2c = w2z + ht * BH;
#pragma unroll
      for (int kk = 0; kk < 4; ++kk) {
        bf16x8 a0 = *(const bf16x8*)&Hs[(w32 + l15) * HPITCH + kk * 32 + quad * 8];
        bf16x8 a1 = *(const bf16x8*)&Hs[(w32 + 16 + l15) * HPITCH + kk * 32 + quad * 8];
#pragma unroll
        for (int j = 0; j < 6; ++j) {
          bf16x8 b = *(const bf16x8*)(w2c + (size_t)(j * 16 + l15) * H_ + kk * 32 + quad * 8);
          acc2[0][j] = MFMA16(a0, b, acc2[0][j]);
          acc2[1][j] = MFMA16(a1, b, acc2[1][j]);
        }
      }
    }
    __syncthreads();   // Hs reads done before next ht's staging writes the aliased Xs
  }

  // ---- epilogue: out[m,p] += gates[m,e] * (acc + b2 (z==0 only)) ----
#pragma unroll
  for (int rt = 0; rt < 2; ++rt) {
#pragma unroll
    for (int r = 0; r < 4; ++r) {
      int m = m0 + w32 + rt * 16 + quad * 4 + r;
      float g = gates[m * E_ + e];
#pragma unroll
      for (int j = 0; j < 6; ++j) {
        int col = j * 16 + l15;
        float v = acc2[rt][j][r];
        if (blockIdx.z == 0) v += b2[e * P_ + col];
        atomicAdd(&out[(size_t)m * P_ + col], g * v);
      }
    }
  }
}

extern "C" void kernel_launch(void* const* d_in, const int* in_sizes, int n_in,
                              void* d_out, int out_size, void* d_ws, size_t ws_size,
                              hipStream_t stream) {
  const float* x  = (const float*)d_in[0];
  const float* te = (const float*)d_in[1];
  const float* Wg = (const float*)d_in[2];
  const float* bg = (const float*)d_in[3];
  const float* W1 = (const float*)d_in[4];
  const float* b1 = (const float*)d_in[5];
  const float* W2 = (const float*)d_in[6];
  const float* b2 = (const float*)d_in[7];
  float* out = (float*)d_out;

  char* ws = (char*)d_ws;
  float* gates = (float*)ws;                                    // 65,536 B
  __bf16* xbf  = (__bf16*)(ws + 65536);                         // 2 MB
  __bf16* w1t  = (__bf16*)(ws + 65536 + 2097152);               // 16 MB
  __bf16* w2t  = (__bf16*)(ws + 65536 + 2097152 + 16777216);    // 3 MB

  k_prep<<<PREP_GRID, 256, 0, stream>>>(x, te, Wg, bg, W1, W2, xbf, w1t, w2t, gates, out);
  k_experts<<<dim3(E_, M_ / BM, ZSPLIT + 1), 256, 0, stream>>>(xbf, w1t, w2t, b1, b2, gates, out);
}

// Round 6
// 194.227 us; speedup vs baseline: 1.2468x; 1.2468x over previous
//
#include <hip/hip_runtime.h>
#include <math.h>

#define B_ 64
#define F_ 32
#define S_ 512
#define P_ 96
#define E_ 8
#define H_ 2048
#define M_ 2048   // B_*F_ rows, m = b*F_ + f

// ---- k_experts tiling (m97-style): 512 threads, 128m x 128h tiles, BK=64 ----
#define BM 128
#define BH 128
#define BK 64
#define ZSPLIT 4
#define HPZ (H_ / ZSPLIT)   // 512 h per z-block
#define NHT (HPZ / BH)      // 4 h-chunks per block
#define NKC (S_ / BK)       // 8 k-chunks
#define HPITCH 136          // 128 + 8 skew

typedef __bf16 bf16x8 __attribute__((ext_vector_type(8)));
typedef __bf16 bf16x4 __attribute__((ext_vector_type(4)));
typedef float f32x4 __attribute__((ext_vector_type(4)));

#define MFMA16(a, b, c) __builtin_amdgcn_mfma_f32_16x16x32_bf16((a), (b), (c), 0, 0, 0)

// async global->LDS, 16B per lane; LDS dest is wave-uniform base + lane*16
#define GLL16(gp, lp) __builtin_amdgcn_global_load_lds(                     \
    (const __attribute__((address_space(1))) void*)(gp),                    \
    (__attribute__((address_space(3))) void*)(lp), 16, 0, 0)

// sigmoid-approx gelu: x * sigmoid(1.702 x)  (absmax 0.0098 measured — 17x margin)
__device__ __forceinline__ float fast_gelu(float x) {
  float e = __builtin_amdgcn_exp2f(-2.45546696f * x);
  return x * __builtin_amdgcn_rcpf(1.0f + e);
}

// =================== k_prep_w1 (256 threads, 256 blocks): W1 strip transpose ===================
// (e, 64-h strip) x all 512 s: [E][S][H] f32 -> w1t [E][H][S] bf16
__global__ __launch_bounds__(256) void k_prep_w1(const float* __restrict__ W1,
                                                 __bf16* __restrict__ w1t) {
  __shared__ __align__(16) __bf16 btile[256 * 68];   // 34,816 B
  const int tid = threadIdx.x;
  int e = blockIdx.x >> 5, hstrip = blockIdx.x & 31;
  const float* src = W1 + (size_t)e * S_ * H_ + hstrip * 64;
  __bf16* dstb = w1t + (size_t)e * H_ * S_ + (size_t)(hstrip * 64) * S_;
#pragma unroll
  for (int pass = 0; pass < 2; ++pass) {
    {
      int rb = tid >> 2;
      int hseg = (tid & 3) * 16;
#pragma unroll
      for (int it = 0; it < 4; ++it) {
        int r = it * 64 + rb;
        const float* srow = src + (size_t)(pass * 256 + r) * H_ + hseg;
#pragma unroll
        for (int k = 0; k < 4; ++k) {
          f32x4 v = *(const f32x4*)(srow + k * 4);
          bf16x4 o = {(__bf16)v[0], (__bf16)v[1], (__bf16)v[2], (__bf16)v[3]};
          *(bf16x4*)&btile[r * 68 + hseg + k * 4] = o;
        }
      }
    }
    __syncthreads();
    {
      int h = tid >> 2;
      int sseg = (tid & 3) * 64;
      __bf16* drow = dstb + (size_t)h * S_ + pass * 256 + sseg;
#pragma unroll
      for (int g = 0; g < 8; ++g) {
        bf16x8 o;
#pragma unroll
        for (int j = 0; j < 8; ++j) o[j] = btile[(sseg + g * 8 + j) * 68 + h];
        *(bf16x8*)(drow + g * 8) = o;
      }
    }
    __syncthreads();
  }
}

// =================== k_prep_rest (256 threads, 1536 blocks) ===================
// blocks [0,512):     W2 [E][H][P] f32 -> w2t [E][P][H] bf16 (64h x 48p tiles)
// blocks [512,1024):  x convert (8 elems/thread)
// blocks [1024,1536): gates (4 rows per block)
__global__ __launch_bounds__(256) void k_prep_rest(const float* __restrict__ x,
                                                   const float* __restrict__ te,
                                                   const float* __restrict__ Wg,
                                                   const float* __restrict__ bg,
                                                   const float* __restrict__ W2,
                                                   __bf16* __restrict__ xbf,
                                                   __bf16* __restrict__ w2t,
                                                   float* __restrict__ gates) {
  __shared__ float tile[64 * 49];
  const int blk = blockIdx.x;
  const int tid = threadIdx.x;

  if (blk < 512) {                        // ---- W2 transpose: tile 64h x 48p
    int e = blk >> 6, hi = (blk >> 1) & 31, ph = blk & 1;
    const float* src = W2 + (size_t)e * H_ * P_ + (size_t)(hi * 64) * P_ + ph * 48;
    {
      int h = tid & 63;
      int seg = tid >> 6;
#pragma unroll
      for (int k = 0; k < 3; ++k) {
        f32x4 v = *(const f32x4*)(src + (size_t)h * P_ + seg * 12 + k * 4);
#pragma unroll
        for (int u = 0; u < 4; ++u) tile[h * 49 + seg * 12 + k * 4 + u] = v[u];
      }
    }
    __syncthreads();
    if (tid < 192) {
      int p = tid >> 2;
      int hb = (tid & 3) * 16;
      __bf16* dst = w2t + (size_t)e * P_ * H_ + (size_t)(ph * 48 + p) * H_ + hi * 64 + hb;
      bf16x8 o0, o1;
#pragma unroll
      for (int k = 0; k < 8; ++k) o0[k] = (__bf16)tile[(hb + k) * 49 + p];
#pragma unroll
      for (int k = 0; k < 8; ++k) o1[k] = (__bf16)tile[(hb + 8 + k) * 49 + p];
      *(bf16x8*)dst = o0;
      *(bf16x8*)(dst + 8) = o1;
    }
    return;
  }
  if (blk < 1024) {                       // ---- x convert
    size_t i = (size_t)(blk - 512) * 2048 + (size_t)tid * 8;
#pragma unroll
    for (int k = 0; k < 2; ++k) {
      f32x4 v = *(const f32x4*)(x + i + k * 4);
      bf16x4 o = {(__bf16)v[0], (__bf16)v[1], (__bf16)v[2], (__bf16)v[3]};
      *(bf16x4*)(xbf + i + k * 4) = o;
    }
    return;
  }
  // ---- gates: one wave per row m
  int wave = tid >> 6, lane = tid & 63;
  int m = (blk - 1024) * 4 + wave;
  const float* trow = te + (size_t)m * S_;
  float acc[E_];
#pragma unroll
  for (int e = 0; e < E_; ++e) acc[e] = 0.f;
  for (int s = lane; s < S_; s += 64) {
    float t = trow[s];
    const f32x4* wgr = (const f32x4*)(Wg + s * E_);
    f32x4 a = wgr[0], b = wgr[1];
    acc[0] += t * a[0]; acc[1] += t * a[1]; acc[2] += t * a[2]; acc[3] += t * a[3];
    acc[4] += t * b[0]; acc[5] += t * b[1]; acc[6] += t * b[2]; acc[7] += t * b[3];
  }
#pragma unroll
  for (int e = 0; e < E_; ++e) {
#pragma unroll
    for (int off = 32; off > 0; off >>= 1) acc[e] += __shfl_xor(acc[e], off, 64);
  }
  if (lane == 0) {
    float lg[E_];
    float m1 = -3.4e38f, m2 = -3.4e38f;
#pragma unroll
    for (int e = 0; e < E_; ++e) {
      float v = acc[e] + bg[e];
      lg[e] = v;
      if (v > m1) { m2 = m1; m1 = v; }
      else if (v > m2) { m2 = v; }
    }
    float den = 0.f, sm[E_];
#pragma unroll
    for (int e = 0; e < E_; ++e) { sm[e] = expf(lg[e] - m1); den += sm[e]; }
    float inv = 1.f / den;
    float dmax = -3.4e38f, dec[E_];
#pragma unroll
    for (int e = 0; e < E_; ++e) {
      float p = sm[e] * inv;
      float d = (lg[e] < m2) ? (10.f * logf(p + 1.f)) : (10.f * (expf(p) - 1.f));
      dec[e] = d;
      dmax = fmaxf(dmax, d);
    }
    float dden = 0.f;
#pragma unroll
    for (int e = 0; e < E_; ++e) { dec[e] = expf(dec[e] - dmax); dden += dec[e]; }
    float dinv = 1.f / dden;
#pragma unroll
    for (int e = 0; e < E_; ++e) gates[m * E_ + e] = dec[e] * dinv;
  }
}

// =================== k_experts: grid (E_, 16, ZSPLIT+1), 512 threads ===================
// R4 structure (proven FETCH=compulsory) at 2x waves: same block count, same grid,
// same 67.6 KB LDS (separate Xs — NO alias), exactly 2 work blocks/CU resident,
// but 512 threads -> 16 waves/CU to hide the per-kc barrier drains.
__global__ __launch_bounds__(512, 4) void k_experts(
    const __bf16* __restrict__ xbf,   // [M][S]
    const __bf16* __restrict__ w1t,   // [E][H][S]
    const __bf16* __restrict__ w2t,   // [E][P][H]
    const float* __restrict__ b1,     // [E][H]
    const float* __restrict__ b2,     // [E][P]
    const float* __restrict__ gates,  // [M][E]
    float* __restrict__ out)          // [M][P] (+2 loss slots)
{
  __shared__ __align__(16) __bf16 W1s[BH * BK];      // 16 KB [h][k] unpadded, swizzled
  __shared__ __align__(16) __bf16 Xs[BM * BK];       // 16 KB [m][k]
  __shared__ __align__(16) __bf16 Hs[BM * HPITCH];   // 34.8 KB -> 67.6 KB total

  const int tid = threadIdx.x;

  if (blockIdx.z == ZSPLIT) {      // ---- loss block (others exit)
    if (blockIdx.x != 0 || blockIdx.y != 0) return;
    float* gsum = (float*)&Hs[0];
    float* cvs  = gsum + F_ * E_;
    float* ents = cvs + F_;
    if (tid < 256) {
      int f = tid >> 3, e = tid & 7;
      float s = 0.f;
      for (int b = 0; b < B_; ++b) s += gates[(size_t)(b * F_ + f) * E_ + e];
      gsum[f * E_ + e] = s;
    }
    __syncthreads();
    if (tid < F_) {
      float mean = 0.f;
#pragma unroll
      for (int k = 0; k < E_; ++k) mean += gsum[tid * E_ + k];
      mean *= (1.f / E_);
      float ss = 0.f;
#pragma unroll
      for (int k = 0; k < E_; ++k) { float d = gsum[tid * E_ + k] - mean; ss += d * d; }
      float var = (float)P_ * ss / (float)(E_ * P_ - 1);
      cvs[tid] = var / (mean * mean + 1e-10f);
      float ent = 0.f;
#pragma unroll
      for (int k = 0; k < E_; ++k) { float g = gsum[tid * E_ + k] * (1.f / B_); ent += -g * logf(g + 1e-8f); }
      ents[tid] = ent * (1.f / E_);
    }
    __syncthreads();
    if (tid == 0) {
      float a = 0.f, b = 0.f;
      for (int k = 0; k < F_; ++k) { a += cvs[k]; b += ents[k]; }
      out[(size_t)M_ * P_ + 0] = a;
      out[(size_t)M_ * P_ + 1] = b;
    }
    return;
  }

  const int wave = tid >> 6, lane = tid & 63;
  const int l15 = lane & 15, quad = lane >> 4;
  const int e = blockIdx.x;
  const int m0 = blockIdx.y * BM;
  const int hz = blockIdx.z * HPZ;

  // staging decomposition: lane -> (row-in-8-group srl, granule sg); swizzle sg^srl
  const int sg = lane & 7;
  const int srl = lane >> 3;
  const int gcol = ((sg ^ srl) * 8);    // swizzled source column (elements)

  const __bf16* xg = xbf + (size_t)(m0 + wave * 8 + srl) * S_ + gcol;
  const __bf16* w1base = w1t + ((size_t)e * H_ + hz + wave * 8 + srl) * S_ + gcol;
  const __bf16* w2z = w2t + (size_t)e * P_ * H_ + hz;

  // GEMM1 wave tile: 32h x 64m  (8 waves cover 128h x 128m)
  const int hq = (wave & 3) * 32;
  const int mq = (wave >> 2) * 64;
  // GEMM2 wave tile: 32m x 48p
  const int mt = wave & 3;
  const int ph = wave >> 2;

  const f32x4 fz = {0.f, 0.f, 0.f, 0.f};
  f32x4 acc2[2][3];
#pragma unroll
  for (int rt = 0; rt < 2; ++rt)
#pragma unroll
    for (int j = 0; j < 3; ++j) acc2[rt][j] = fz;

  for (int ht = 0; ht < NHT; ++ht) {
    const __bf16* w1g = w1base + (size_t)(ht * BH) * S_;
    f32x4 acc1[2][4];
#pragma unroll
    for (int i = 0; i < 2; ++i)
#pragma unroll
      for (int j = 0; j < 4; ++j) acc1[i][j] = fz;

    for (int kc = 0; kc < NKC; ++kc) {
#pragma unroll
      for (int p = 0; p < 2; ++p) {     // 512 threads: 2 passes of 64 rows
        GLL16(w1g + (size_t)(p * 64) * S_ + kc * BK, &W1s[(p * 64 + wave * 8) * BK]);
        GLL16(xg  + (size_t)(p * 64) * S_ + kc * BK, &Xs[(p * 64 + wave * 8) * BK]);
      }
      __syncthreads();   // vmcnt drain + barrier: staged tiles visible
#pragma unroll
      for (int kk = 0; kk < 2; ++kk) {
        bf16x8 a[2], b[4];
#pragma unroll
        for (int i = 0; i < 2; ++i) {
          int r = hq + i * 16 + l15;
          int g = kk * 4 + quad;
          a[i] = *(const bf16x8*)&W1s[r * BK + ((g ^ (r & 7)) * 8)];
        }
#pragma unroll
        for (int j = 0; j < 4; ++j) {
          int r = mq + j * 16 + l15;
          int g = kk * 4 + quad;
          b[j] = *(const bf16x8*)&Xs[r * BK + ((g ^ (r & 7)) * 8)];
        }
#pragma unroll
        for (int i = 0; i < 2; ++i)
#pragma unroll
          for (int j = 0; j < 4; ++j)
            acc1[i][j] = MFMA16(a[i], b[j], acc1[i][j]);
      }
      __syncthreads();   // reads done before next stage overwrites
    }

    // bias + gelu -> Hs[m][h] (C-layout: col=l15=m, row=quad*4+r=h-local)
    {
      const float* b1w = b1 + (size_t)e * H_ + hz + ht * BH + hq;
#pragma unroll
      for (int i = 0; i < 2; ++i) {
        f32x4 bv = *(const f32x4*)(b1w + i * 16 + quad * 4);
#pragma unroll
        for (int j = 0; j < 4; ++j) {
          bf16x4 hv;
#pragma unroll
          for (int r = 0; r < 4; ++r)
            hv[r] = (__bf16)fast_gelu(acc1[i][j][r] + bv[r]);
          *(bf16x4*)&Hs[(mq + j * 16 + l15) * HPITCH + hq + i * 16 + quad * 4] = hv;
        }
      }
    }
    __syncthreads();

    // GEMM2: acc2 += Hs[128m x 128h] @ W2chunk[128h x 96p]; B-frags direct from L1/L2-hot w2t
    {
      const __bf16* w2c = w2z + ht * BH;
#pragma unroll
      for (int kk = 0; kk < 4; ++kk) {
        bf16x8 a0 = *(const bf16x8*)&Hs[(mt * 32 + l15) * HPITCH + kk * 32 + quad * 8];
        bf16x8 a1 = *(const bf16x8*)&Hs[(mt * 32 + 16 + l15) * HPITCH + kk * 32 + quad * 8];
#pragma unroll
        for (int j = 0; j < 3; ++j) {
          bf16x8 b = *(const bf16x8*)(w2c + (size_t)(ph * 48 + j * 16 + l15) * H_ + kk * 32 + quad * 8);
          acc2[0][j] = MFMA16(a0, b, acc2[0][j]);
          acc2[1][j] = MFMA16(a1, b, acc2[1][j]);
        }
      }
    }
    // next ht's k-loop first barrier protects Hs (staging writes W1s/Xs only,
    // which were last read before that same barrier) — wait: Xs/W1s rewritten
    // right after; their last reads were pre-barrier in this iteration. Hs reads
    // (GEMM2) complete before the next gelu write, which is after a full k-loop
    // of barriers. Safe.
  }

  // ---- epilogue: out[m,p] += gates[m,e] * (acc + b2 (z==0 only)) ----
#pragma unroll
  for (int rt = 0; rt < 2; ++rt) {
#pragma unroll
    for (int r = 0; r < 4; ++r) {
      int m = m0 + mt * 32 + rt * 16 + quad * 4 + r;
      float g = gates[m * E_ + e];
#pragma unroll
      for (int j = 0; j < 3; ++j) {
        int col = ph * 48 + j * 16 + l15;
        float v = acc2[rt][j][r];
        if (blockIdx.z == 0) v += b2[e * P_ + col];
        atomicAdd(&out[(size_t)m * P_ + col], g * v);
      }
    }
  }
}

extern "C" void kernel_launch(void* const* d_in, const int* in_sizes, int n_in,
                              void* d_out, int out_size, void* d_ws, size_t ws_size,
                              hipStream_t stream) {
  const float* x  = (const float*)d_in[0];
  const float* te = (const float*)d_in[1];
  const float* Wg = (const float*)d_in[2];
  const float* bg = (const float*)d_in[3];
  const float* W1 = (const float*)d_in[4];
  const float* b1 = (const float*)d_in[5];
  const float* W2 = (const float*)d_in[6];
  const float* b2 = (const float*)d_in[7];
  float* out = (float*)d_out;

  char* ws = (char*)d_ws;
  float* gates = (float*)ws;                                    // 65,536 B
  __bf16* xbf  = (__bf16*)(ws + 65536);                         // 2 MB
  __bf16* w1t  = (__bf16*)(ws + 65536 + 2097152);               // 16 MB
  __bf16* w2t  = (__bf16*)(ws + 65536 + 2097152 + 16777216);    // 3 MB

  hipMemsetAsync(d_out, 0, (size_t)out_size * sizeof(float), stream);
  k_prep_w1<<<256, 256, 0, stream>>>(W1, w1t);
  k_prep_rest<<<1536, 256, 0, stream>>>(x, te, Wg, bg, W2, xbf, w2t, gates);
  k_experts<<<dim3(E_, M_ / BM, ZSPLIT + 1), 512, 0, stream>>>(xbf, w1t, w2t, b1, b2, gates, out);
}